// Round 1
// baseline (594.379 us; speedup 1.0000x reference)
//
#include <hip/hip_runtime.h>
#include <hip/hip_fp16.h>
#include <cstdint>

// Problem constants (fixed by the reference)
#define NROWS 65536
#define DIM   512    // D
#define KDIM  256    // K
#define ODIM  512    // O
#define DEG   8

typedef _Float16 f16x8 __attribute__((ext_vector_type(8)));
typedef float    f32x4 __attribute__((ext_vector_type(4)));

// ---- helpers -------------------------------------------------------------

// async 16B global->LDS (width=16 => global_load_lds_dwordx4). Dest is
// wave-uniform base + lane*16 by HW rule; we arrange addresses accordingly.
__device__ __forceinline__ void gld_lds16(const void* g, void* l) {
  __builtin_amdgcn_global_load_lds(
      (const __attribute__((address_space(1))) unsigned int*)g,
      (__attribute__((address_space(3))) unsigned int*)l, 16, 0, 0);
}

__device__ __forceinline__ unsigned pack2h(float a, float b) {
  union { _Float16 h[2]; unsigned u; } x;
  x.h[0] = (_Float16)a; x.h[1] = (_Float16)b;
  return x.u;
}

// Swizzled byte offset inside a tile whose rows are 64 f16 (=128B = 8 chunks
// of 16B). chunk c of row r lives at slot (c+r)&7 -> conflict-free b128 reads.
__device__ __forceinline__ int swz(int row, int chunk) {
  return (row << 7) | (((chunk + row) & 7) << 4);
}

// ---- kernel 0: convert T (fold a_n) and C_w to fp16 ----------------------

__global__ void k_convert(const float* __restrict__ T,
                          const float* __restrict__ Cw,
                          _Float16* __restrict__ Tb,
                          _Float16* __restrict__ Cwb) {
  const int TN = DEG * KDIM * DIM;  // 1048576
  int e = (blockIdx.x * 256 + threadIdx.x) * 4;
  if (e < TN) {
    int n = e >> 17;  // / (KDIM*DIM)
    // Tb[j] holds degree j+1: scale 1 for j=0, (2j+1)/(j+1) for j>=1
    float s = (n == 0) ? 1.0f : (float)(2 * n + 1) / (float)(n + 1);
    float4 v = *(const float4*)(T + e);
    uint2 p; p.x = pack2h(v.x * s, v.y * s); p.y = pack2h(v.z * s, v.w * s);
    *(uint2*)((char*)Tb + (size_t)e * 2) = p;
  } else {
    int o = e - TN;
    if (o < ODIM * KDIM) {
      float4 v = *(const float4*)(Cw + o);
      uint2 p; p.x = pack2h(v.x, v.y); p.y = pack2h(v.z, v.w);
      *(uint2*)((char*)Cwb + (size_t)o * 2) = p;
    }
  }
}

// ---- kernel 1: fused [Nx512]x[512x2048] GEMM + degree recurrence ---------
// Block tile: 128 rows x 32 u-cols x 8 degrees. Wave w: rows w*32..w*32+31.
// acc[deg][mfrag][kfrag] lets the Legendre recurrence run per-thread.

__launch_bounds__(256, 2)
__global__ void k_poly(const float* __restrict__ z,
                       const float* __restrict__ T0,
                       const _Float16* __restrict__ Tb,
                       _Float16* __restrict__ u8) {
  __shared__ __align__(16) uint16_t As[128 * 64];  // 16 KB, z tile (fp16)
  __shared__ __align__(16) uint16_t Bs[256 * 64];  // 32 KB, Tb tile (8 deg x 32 k)

  const int tid = threadIdx.x;
  const int wave = tid >> 6, lane = tid & 63;

  // super-tile swizzle: 16 row-tiles x 8 k-groups per super (z reuse in L2)
  const int id = blockIdx.x;
  const int super = id >> 7, rem = id & 127;
  const int kg = rem >> 4;                    // 0..7  (u-col group)
  const int rt = (super << 4) | (rem & 15);   // 0..511 (row tile)
  const int r0 = rt << 7;                     // *128
  const int k0 = kg << 5;                     // *32

  const int m_l = lane & 15, kq = lane >> 4;  // frag row / k-quad
  const int wrow = wave << 5;                 // 32 rows per wave

  f32x4 acc[DEG][2][2];
#pragma unroll
  for (int n = 0; n < DEG; n++)
#pragma unroll
    for (int a = 0; a < 2; a++)
#pragma unroll
      for (int b = 0; b < 2; b++)
        acc[n][a][b] = (f32x4){0.f, 0.f, 0.f, 0.f};

  for (int it = 0; it < DIM / 64; it++) {
    const int d0 = it << 6;
    __syncthreads();  // previous iter's LDS reads done

    // B: 256 rows (deg*32+k) x 64 d, async direct-to-LDS, swizzle-inverted
#pragma unroll
    for (int j = 0; j < 8; j++) {
      int lin = (j << 8) + tid;            // 0..2047 chunk slots
      int row = lin >> 3;
      int c = ((lin & 7) - row) & 7;       // which chunk lands in this slot
      int n = row >> 5, kk = row & 31;
      const _Float16* g = Tb + (size_t)((n << 8) + k0 + kk) * DIM + d0 + (c << 3);
      gld_lds16(g, (char*)Bs + (lin << 4));
    }
    // A: z fp32 -> fp16 inline, ds_write 8B into swizzled layout
#pragma unroll
    for (int j = 0; j < 8; j++) {
      int lin = (j << 8) + tid;            // float4 units, 0..2047
      int row = lin >> 4, c4 = lin & 15;
      float4 v = *(const float4*)(z + (size_t)(r0 + row) * DIM + d0 + (c4 << 2));
      uint2 p; p.x = pack2h(v.x, v.y); p.y = pack2h(v.z, v.w);
      int off = (row << 7) | ((((c4 >> 1) + row) & 7) << 4) | ((c4 & 1) << 3);
      *(uint2*)((char*)As + off) = p;
    }
    __syncthreads();  // drains vmcnt (async LDS) + lgkmcnt

#pragma unroll
    for (int ks = 0; ks < 2; ks++) {
      const int chunk = (ks << 2) + kq;
      f16x8 af[2];
#pragma unroll
      for (int mf = 0; mf < 2; mf++)
        af[mf] = *(const f16x8*)((char*)As + swz(wrow + (mf << 4) + m_l, chunk));
#pragma unroll
      for (int n = 0; n < DEG; n++) {
#pragma unroll
        for (int kf = 0; kf < 2; kf++) {
          f16x8 bv = *(const f16x8*)((char*)Bs + swz((n << 5) + (kf << 4) + m_l, chunk));
#pragma unroll
          for (int mf = 0; mf < 2; mf++)
            acc[n][mf][kf] = __builtin_amdgcn_mfma_f32_16x16x32_f16(
                af[mf], bv, acc[n][mf][kf], 0, 0, 0);
        }
      }
    }
  }

  // Legendre recurrence per accumulator element, then store u8 as fp16.
  // C/D layout: col = lane&15, row = (lane>>4)*4 + reg  [m89-verified]
  const float bcoef[7] = {1.f/2.f, 2.f/3.f, 3.f/4.f, 4.f/5.f,
                          5.f/6.f, 6.f/7.f, 7.f/8.f};
#pragma unroll
  for (int kf = 0; kf < 2; kf++) {
    const int col = k0 + (kf << 4) + m_l;
    const float t0v = T0[col];
#pragma unroll
    for (int mf = 0; mf < 2; mf++) {
      f32x4 up2 = {t0v, t0v, t0v, t0v};
      f32x4 up1 = acc[0][mf][kf];
#pragma unroll
      for (int n = 2; n <= DEG; n++) {
        f32x4 cur = acc[n - 1][mf][kf] * up1 - bcoef[n - 2] * up2;
        up2 = up1; up1 = cur;
      }
      const int rbase = r0 + wrow + (mf << 4) + (kq << 2);
#pragma unroll
      for (int r = 0; r < 4; r++)
        u8[(size_t)(rbase + r) * KDIM + col] = (_Float16)up1[r];
    }
  }
}

// ---- kernel 2: out[N,512] = u8[N,256] @ Cw^T + C_b (fp32 out) ------------
// Block tile 128 rows x 64 out-cols; wave: 32 rows x 64 cols.

__launch_bounds__(256)
__global__ void k_out(const _Float16* __restrict__ u8,
                      const _Float16* __restrict__ Cwb,
                      const float* __restrict__ Cb,
                      float* __restrict__ out) {
  __shared__ __align__(16) uint16_t As[128 * 64];  // 16 KB u8 tile
  __shared__ __align__(16) uint16_t Bs[64 * 64];   //  8 KB Cw tile

  const int tid = threadIdx.x;
  const int wave = tid >> 6, lane = tid & 63;

  const int id = blockIdx.x;
  const int super = id >> 7, rem = id & 127;
  const int cg = rem >> 4;                    // 0..7  out-col group (64 cols)
  const int rt = (super << 4) | (rem & 15);   // 0..511 row tile
  const int r0 = rt << 7;
  const int c0 = cg << 6;

  const int m_l = lane & 15, kq = lane >> 4;
  const int wrow = wave << 5;

  f32x4 acc[2][4];
#pragma unroll
  for (int a = 0; a < 2; a++)
#pragma unroll
    for (int b = 0; b < 4; b++)
      acc[a][b] = (f32x4){0.f, 0.f, 0.f, 0.f};

  for (int it = 0; it < KDIM / 64; it++) {
    const int d0 = it << 6;
    __syncthreads();
#pragma unroll
    for (int j = 0; j < 4; j++) {           // A: 128 rows x 8 chunks
      int lin = (j << 8) + tid;
      int row = lin >> 3;
      int c = ((lin & 7) - row) & 7;
      gld_lds16(u8 + (size_t)(r0 + row) * KDIM + d0 + (c << 3),
                (char*)As + (lin << 4));
    }
#pragma unroll
    for (int j = 0; j < 2; j++) {           // B: 64 rows x 8 chunks
      int lin = (j << 8) + tid;
      int row = lin >> 3;
      int c = ((lin & 7) - row) & 7;
      gld_lds16(Cwb + (size_t)(c0 + row) * KDIM + d0 + (c << 3),
                (char*)Bs + (lin << 4));
    }
    __syncthreads();

#pragma unroll
    for (int ks = 0; ks < 2; ks++) {
      const int chunk = (ks << 2) + kq;
      f16x8 af[2];
#pragma unroll
      for (int mf = 0; mf < 2; mf++)
        af[mf] = *(const f16x8*)((char*)As + swz(wrow + (mf << 4) + m_l, chunk));
#pragma unroll
      for (int kf = 0; kf < 4; kf++) {
        f16x8 bv = *(const f16x8*)((char*)Bs + swz((kf << 4) + m_l, chunk));
#pragma unroll
        for (int mf = 0; mf < 2; mf++)
          acc[mf][kf] = __builtin_amdgcn_mfma_f32_16x16x32_f16(
              af[mf], bv, acc[mf][kf], 0, 0, 0);
      }
    }
  }

#pragma unroll
  for (int kf = 0; kf < 4; kf++) {
    const int col = c0 + (kf << 4) + m_l;
    const float cb = Cb[col];
#pragma unroll
    for (int mf = 0; mf < 2; mf++) {
      const int rbase = r0 + wrow + (mf << 4) + (kq << 2);
#pragma unroll
      for (int r = 0; r < 4; r++)
        out[(size_t)(rbase + r) * ODIM + col] = acc[mf][kf][r] + cb;
    }
  }
}

// ---- launch --------------------------------------------------------------

extern "C" void kernel_launch(void* const* d_in, const int* in_sizes, int n_in,
                              void* d_out, int out_size, void* d_ws, size_t ws_size,
                              hipStream_t stream) {
  const float* z  = (const float*)d_in[0];
  const float* T0 = (const float*)d_in[1];
  const float* T  = (const float*)d_in[2];
  const float* Cw = (const float*)d_in[3];
  const float* Cb = (const float*)d_in[4];
  float* out = (float*)d_out;

  // ws layout: Tb 2MB | Cwb 256KB | u8 32MB  (total ~34.25 MB)
  char* ws = (char*)d_ws;
  _Float16* Tb  = (_Float16*)ws;
  _Float16* Cwb = (_Float16*)(ws + (2u << 20));
  _Float16* u8  = (_Float16*)(ws + (2u << 20) + (256u << 10));

  k_convert<<<1152, 256, 0, stream>>>(T, Cw, Tb, Cwb);
  k_poly<<<4096, 256, 0, stream>>>(z, T0, Tb, u8);
  k_out<<<4096, 256, 0, stream>>>(u8, Cwb, Cb, out);
}

// Round 2
// 389.212 us; speedup vs baseline: 1.5271x; 1.5271x over previous
//
#include <hip/hip_runtime.h>
#include <hip/hip_fp16.h>
#include <cstdint>

// Problem constants (fixed by the reference)
#define NROWS 65536
#define DIM   512    // D
#define KDIM  256    // K
#define ODIM  512    // O
#define DEG   8
#define ZN    (NROWS * DIM)        // 33554432 z elements
#define TN    (DEG * KDIM * DIM)   // 1048576 T elements
#define CWN   (ODIM * KDIM)        // 131072 C_w elements

typedef _Float16 f16x8 __attribute__((ext_vector_type(8)));
typedef float    f32x4 __attribute__((ext_vector_type(4)));

// ---- helpers -------------------------------------------------------------

// async 16B global->LDS (global_load_lds_dwordx4). LDS dest is wave-uniform
// base + lane*16 by HW rule; all our slot mappings honor that.
__device__ __forceinline__ void gld_lds16(const void* g, void* l) {
  __builtin_amdgcn_global_load_lds(
      (const __attribute__((address_space(1))) unsigned int*)g,
      (__attribute__((address_space(3))) unsigned int*)l, 16, 0, 0);
}

__device__ __forceinline__ unsigned pack2h(float a, float b) {
  union { _Float16 h[2]; unsigned u; } x;
  x.h[0] = (_Float16)a; x.h[1] = (_Float16)b;
  return x.u;
}

// Swizzled byte offset in a tile of 64-half rows (128B = 8 x 16B chunks).
// chunk c of row r lives at slot (c+r)&7 -> conflict-free ds_read_b128.
__device__ __forceinline__ int swz(int row, int chunk) {
  return (row << 7) | (((chunk + row) & 7) << 4);
}

// ---- kernel 0: fp32->fp16 conversions (z, T with a_n folded, C_w) --------

__global__ void k_convert(const float* __restrict__ z,
                          const float* __restrict__ T,
                          const float* __restrict__ Cw,
                          _Float16* __restrict__ z16,
                          _Float16* __restrict__ Tb,
                          _Float16* __restrict__ Cwb) {
  long e = ((long)blockIdx.x * 256 + threadIdx.x) * 4;
  const float* src;
  _Float16* dst;
  float s = 1.0f;
  if (e < ZN) {
    src = z + e; dst = z16 + e;
  } else {
    long o = e - ZN;
    if (o < TN) {
      int n = (int)(o >> 17);  // / (KDIM*DIM); Tb[n] holds degree n+1
      s = (n == 0) ? 1.0f : (float)(2 * n + 1) / (float)(n + 1);
      src = T + o; dst = Tb + o;
    } else {
      long c = o - TN;
      if (c >= CWN) return;
      src = Cw + c; dst = Cwb + c;
    }
  }
  float4 v = *(const float4*)src;
  uint2 p; p.x = pack2h(v.x * s, v.y * s); p.y = pack2h(v.z * s, v.w * s);
  *(uint2*)dst = p;
}

// ---- kernel 1: fused GEMM [Nx512]x[512x(16x8deg)] + degree recurrence ----
// Block tile: 128 rows x 16 u-cols x 8 degrees. acc[deg][mf] per thread so
// the Legendre recurrence is register-local. All staging via async
// global_load_lds (z pre-converted to fp16) — no VALU on the staging path.

__launch_bounds__(256, 3)
__global__ void k_poly(const _Float16* __restrict__ z16,
                       const float* __restrict__ T0,
                       const _Float16* __restrict__ Tb,
                       _Float16* __restrict__ u8) {
  __shared__ __align__(16) uint16_t As[128 * 64];  // 16 KB z tile
  __shared__ __align__(16) uint16_t Bs[128 * 64];  // 16 KB Tb tile (8deg x 16k)

  const int tid = threadIdx.x;
  const int wave = tid >> 6, lane = tid & 63;

  // super-tile: 16 row-tiles x 16 k-groups -> z16 slice (2MB) + Tb (2MB) ~ L2
  const int id = blockIdx.x;
  const int super = id >> 8, rem = id & 255;
  const int kg = rem >> 4;                    // 0..15 (16 u-cols each)
  const int rt = (super << 4) | (rem & 15);   // 0..511 row tile
  const int r0 = rt << 7;
  const int k0 = kg << 4;

  const int m_l = lane & 15, kq = lane >> 4;
  const int wrow = wave << 5;                 // 32 rows per wave

  f32x4 acc[DEG][2];
#pragma unroll
  for (int n = 0; n < DEG; n++)
#pragma unroll
    for (int a = 0; a < 2; a++)
      acc[n][a] = (f32x4){0.f, 0.f, 0.f, 0.f};

  // Hoisted staging addresses. Slot lin=j*256+tid, row=lin>>3,
  // c=((lin&7)-row)&7 inverts the swizzle on the global side.
  const _Float16* aptr[4];
  const _Float16* bptr[4];
  int lofs[4];
#pragma unroll
  for (int j = 0; j < 4; j++) {
    int lin = (j << 8) + tid;
    int row = lin >> 3;
    int c = ((lin & 7) - row) & 7;
    lofs[j] = lin << 4;
    aptr[j] = z16 + (size_t)(r0 + row) * DIM + (c << 3);
    int n = row >> 4, kk = row & 15;
    bptr[j] = Tb + (size_t)((n << 8) + k0 + kk) * DIM + (c << 3);
  }

  for (int it = 0; it < DIM / 64; it++) {
    __syncthreads();  // previous iter's LDS reads done
#pragma unroll
    for (int j = 0; j < 4; j++) gld_lds16(aptr[j], (char*)As + lofs[j]);
#pragma unroll
    for (int j = 0; j < 4; j++) gld_lds16(bptr[j], (char*)Bs + lofs[j]);
#pragma unroll
    for (int j = 0; j < 4; j++) { aptr[j] += 64; bptr[j] += 64; }
    __syncthreads();  // drains async loads

#pragma unroll
    for (int ks = 0; ks < 2; ks++) {
      const int chunk = (ks << 2) + kq;
      f16x8 af[2];
#pragma unroll
      for (int mf = 0; mf < 2; mf++)
        af[mf] = *(const f16x8*)((char*)As + swz(wrow + (mf << 4) + m_l, chunk));
#pragma unroll
      for (int n = 0; n < DEG; n++) {
        f16x8 bv = *(const f16x8*)((char*)Bs + swz((n << 4) + m_l, chunk));
#pragma unroll
        for (int mf = 0; mf < 2; mf++)
          acc[n][mf] = __builtin_amdgcn_mfma_f32_16x16x32_f16(
              af[mf], bv, acc[n][mf], 0, 0, 0);
      }
    }
  }

  // Legendre recurrence per accumulator element, store u8 fp16.
  // C/D layout: col = lane&15, row = (lane>>4)*4 + reg  [m89-verified]
  const float bcoef[7] = {1.f/2.f, 2.f/3.f, 3.f/4.f, 4.f/5.f,
                          5.f/6.f, 6.f/7.f, 7.f/8.f};
  const int col = k0 + m_l;
  const float t0v = T0[col];
#pragma unroll
  for (int mf = 0; mf < 2; mf++) {
    f32x4 up2 = {t0v, t0v, t0v, t0v};
    f32x4 up1 = acc[0][mf];
#pragma unroll
    for (int n = 2; n <= DEG; n++) {
      f32x4 cur = acc[n - 1][mf] * up1 - bcoef[n - 2] * up2;
      up2 = up1; up1 = cur;
    }
    const int rbase = r0 + wrow + (mf << 4) + (kq << 2);
#pragma unroll
    for (int r = 0; r < 4; r++)
      u8[(size_t)(rbase + r) * KDIM + col] = (_Float16)up1[r];
  }
}

// ---- kernel 2: out[N,512] = u8[N,256] @ Cw^T + C_b (fp32 out) ------------
// Block tile 128 rows x 64 out-cols; 4 K-iterations of 64.

__launch_bounds__(256, 4)
__global__ void k_out(const _Float16* __restrict__ u8,
                      const _Float16* __restrict__ Cwb,
                      const float* __restrict__ Cb,
                      float* __restrict__ out) {
  __shared__ __align__(16) uint16_t As[128 * 64];  // 16 KB u8 tile
  __shared__ __align__(16) uint16_t Bs[64 * 64];   //  8 KB Cw tile

  const int tid = threadIdx.x;
  const int wave = tid >> 6, lane = tid & 63;

  const int id = blockIdx.x;
  const int super = id >> 7, rem = id & 127;
  const int cg = rem >> 4;                    // 0..7 out-col group (64)
  const int rt = (super << 4) | (rem & 15);   // 0..511 row tile
  const int r0 = rt << 7;
  const int c0 = cg << 6;

  const int m_l = lane & 15, kq = lane >> 4;
  const int wrow = wave << 5;

  f32x4 acc[2][4];
#pragma unroll
  for (int a = 0; a < 2; a++)
#pragma unroll
    for (int b = 0; b < 4; b++)
      acc[a][b] = (f32x4){0.f, 0.f, 0.f, 0.f};

  const _Float16* aptr[4];
  const _Float16* bptr[2];
  int lofsA[4], lofsB[2];
#pragma unroll
  for (int j = 0; j < 4; j++) {
    int lin = (j << 8) + tid;
    int row = lin >> 3;
    int c = ((lin & 7) - row) & 7;
    lofsA[j] = lin << 4;
    aptr[j] = u8 + (size_t)(r0 + row) * KDIM + (c << 3);
  }
#pragma unroll
  for (int j = 0; j < 2; j++) {
    int lin = (j << 8) + tid;
    int row = lin >> 3;
    int c = ((lin & 7) - row) & 7;
    lofsB[j] = lin << 4;
    bptr[j] = Cwb + (size_t)(c0 + row) * KDIM + (c << 3);
  }

  for (int it = 0; it < KDIM / 64; it++) {
    __syncthreads();
#pragma unroll
    for (int j = 0; j < 4; j++) gld_lds16(aptr[j], (char*)As + lofsA[j]);
#pragma unroll
    for (int j = 0; j < 2; j++) gld_lds16(bptr[j], (char*)Bs + lofsB[j]);
#pragma unroll
    for (int j = 0; j < 4; j++) aptr[j] += 64;
#pragma unroll
    for (int j = 0; j < 2; j++) bptr[j] += 64;
    __syncthreads();

#pragma unroll
    for (int ks = 0; ks < 2; ks++) {
      const int chunk = (ks << 2) + kq;
      f16x8 af[2];
#pragma unroll
      for (int mf = 0; mf < 2; mf++)
        af[mf] = *(const f16x8*)((char*)As + swz(wrow + (mf << 4) + m_l, chunk));
#pragma unroll
      for (int kf = 0; kf < 4; kf++) {
        f16x8 bv = *(const f16x8*)((char*)Bs + swz((kf << 4) + m_l, chunk));
#pragma unroll
        for (int mf = 0; mf < 2; mf++)
          acc[mf][kf] = __builtin_amdgcn_mfma_f32_16x16x32_f16(
              af[mf], bv, acc[mf][kf], 0, 0, 0);
      }
    }
  }

#pragma unroll
  for (int kf = 0; kf < 4; kf++) {
    const int col = c0 + (kf << 4) + m_l;
    const float cb = Cb[col];
#pragma unroll
    for (int mf = 0; mf < 2; mf++) {
      const int rbase = r0 + wrow + (mf << 4) + (kq << 2);
#pragma unroll
      for (int r = 0; r < 4; r++)
        out[(size_t)(rbase + r) * ODIM + col] = acc[mf][kf][r] + cb;
    }
  }
}

// ---- launch --------------------------------------------------------------

extern "C" void kernel_launch(void* const* d_in, const int* in_sizes, int n_in,
                              void* d_out, int out_size, void* d_ws, size_t ws_size,
                              hipStream_t stream) {
  const float* z  = (const float*)d_in[0];
  const float* T0 = (const float*)d_in[1];
  const float* T  = (const float*)d_in[2];
  const float* Cw = (const float*)d_in[3];
  const float* Cb = (const float*)d_in[4];
  float* out = (float*)d_out;

  // ws layout: z16 64MB | Tb 2MB | Cwb 256KB | u8 32MB  (total ~98.25 MB)
  char* ws = (char*)d_ws;
  _Float16* z16 = (_Float16*)ws;
  _Float16* Tb  = (_Float16*)(ws + (size_t)ZN * 2);
  _Float16* Cwb = (_Float16*)(ws + (size_t)ZN * 2 + (size_t)TN * 2);
  _Float16* u8  = (_Float16*)(ws + (size_t)ZN * 2 + (size_t)TN * 2 + (size_t)CWN * 2);

  // (ZN+TN+CWN)/4 threads / 256 = 33920 blocks exactly
  k_convert<<<33920, 256, 0, stream>>>(z, T, Cw, z16, Tb, Cwb);
  k_poly<<<8192, 256, 0, stream>>>(z16, T0, Tb, u8);
  k_out<<<4096, 256, 0, stream>>>(u8, Cwb, Cb, out);
}